// Round 1
// baseline (313.584 us; speedup 1.0000x reference)
//
#include <hip/hip_runtime.h>

#define HH 512
#define WW 512
#define CC 3
#define PADDIM 544                      // 512 + 2*16
#define PADELEMS (CC * PADDIM * PADDIM) // 887808
#define NB 128                          // kernel blocks per dim
#define KSTR 16384                      // 128*128 stride between taps

// ---------------- pad kernel: edge-replicate into workspace ----------------
__global__ __launch_bounds__(256) void pad_kernel(const float* __restrict__ img,
                                                  float* __restrict__ pad) {
    int idx = blockIdx.x * 256 + threadIdx.x;
    if (idx >= PADELEMS) return;
    int c  = idx / (PADDIM * PADDIM);
    int r  = idx - c * (PADDIM * PADDIM);
    int py = r / PADDIM;
    int px = r - py * PADDIM;
    int iy = min(max(py - 16, 0), HH - 1);
    int ix = min(max(px - 16, 0), WW - 1);
    pad[idx] = img[(c * HH + iy) * WW + ix];
}

// ---------------- main kernel ----------------
// Thread -> (y, wb): computes out[c][y][4*wb .. 4*wb+3] for c = 0..2 (12 outputs),
// over a u-subrange (grid split in 2 parts for occupancy); parts combine via atomicAdd.
// Block (256 thr) = 64 wb  x 4 dy  (one full kernel-block row h), so each weight
// line is reused by 12 threads of the same workgroup via L1.
template <bool PADDED>
__global__ __launch_bounds__(256, 2) void reblur_kernel(const float* __restrict__ src,
                                                        const float* __restrict__ Kern,
                                                        float* __restrict__ out) {
    const int b    = blockIdx.x;
    const int part = b >> 8;   // 0 or 1  (u-range split)
    const int bb   = b & 255;
    const int h    = bb >> 1;  // kernel-block row 0..127
    const int wt   = bb & 1;   // w-tile 0..1
    const int wb   = wt * 64 + (threadIdx.x & 63); // kernel-block col 0..127
    const int dy   = threadIdx.x >> 6;             // row within block, wave-uniform
    const int y    = 4 * h + dy;
    const int u0   = part ? 17 : 0;
    const int u1   = part ? 33 : 17;

    float acc[CC][4];
#pragma unroll
    for (int c = 0; c < CC; ++c)
#pragma unroll
        for (int oj = 0; oj < 4; ++oj) acc[c][oj] = 0.0f;

    const float* kb = Kern + h * NB; // uniform scalar base; + wb per lane

#pragma unroll 1
    for (int u = u0; u < u1; ++u) {
        float row[CC][36];
        if (PADDED) {
            const float* rb = src + ((y + u) * PADDIM + 4 * wb);
#pragma unroll
            for (int c = 0; c < CC; ++c) {
                const float* rc = rb + c * (PADDIM * PADDIM);
#pragma unroll
                for (int j = 0; j < 9; ++j) {
                    const float4 t = *reinterpret_cast<const float4*>(rc + 4 * j);
                    row[c][4 * j + 0] = t.x;
                    row[c][4 * j + 1] = t.y;
                    row[c][4 * j + 2] = t.z;
                    row[c][4 * j + 3] = t.w;
                }
            }
        } else {
            const int iy = min(max(y + u - 16, 0), HH - 1);
#pragma unroll
            for (int c = 0; c < CC; ++c)
#pragma unroll
                for (int e = 0; e < 36; ++e) {
                    const int ix = min(max(4 * wb + e - 16, 0), WW - 1);
                    row[c][e]    = src[(c * HH + iy) * WW + ix];
                }
        }

        // prefetch this tap-row's 33 weights (batched loads -> latency hiding)
        float wv[33];
#pragma unroll
        for (int v = 0; v < 33; ++v) wv[v] = kb[(u * 33 + v) * KSTR + wb];

#pragma unroll
        for (int v = 0; v < 33; ++v) {
            const float wgt = wv[v];
#pragma unroll
            for (int c = 0; c < CC; ++c)
#pragma unroll
                for (int oj = 0; oj < 4; ++oj)
                    acc[c][oj] = fmaf(row[c][v + oj], wgt, acc[c][oj]);
        }
    }

#pragma unroll
    for (int c = 0; c < CC; ++c) {
        float* op = out + (c * HH + y) * WW + 4 * wb;
#pragma unroll
        for (int oj = 0; oj < 4; ++oj) atomicAdd(op + oj, acc[c][oj]);
    }
}

extern "C" void kernel_launch(void* const* d_in, const int* in_sizes, int n_in,
                              void* d_out, int out_size, void* d_ws, size_t ws_size,
                              hipStream_t stream) {
    const float* img  = (const float*)d_in[0];
    const float* Kern = (const float*)d_in[1];
    float* out        = (float*)d_out;

    // output accumulated via atomicAdd from the two u-range parts -> zero it first
    hipMemsetAsync(d_out, 0, (size_t)out_size * sizeof(float), stream);

    if (ws_size >= (size_t)PADELEMS * sizeof(float)) {
        float* pad = (float*)d_ws;
        pad_kernel<<<(PADELEMS + 255) / 256, 256, 0, stream>>>(img, pad);
        reblur_kernel<true><<<512, 256, 0, stream>>>(pad, Kern, out);
    } else {
        reblur_kernel<false><<<512, 256, 0, stream>>>(img, Kern, out);
    }
}